// Round 8
// baseline (446.639 us; speedup 1.0000x reference)
//
#include <hip/hip_runtime.h>
#include <hip/hip_bf16.h>

#define VOCAB 32000
#define EMBED 1024
#define MTOK  4096   // B*T = 2*2048

typedef short bf16x8 __attribute__((ext_vector_type(8)));
typedef short short4v __attribute__((ext_vector_type(4)));
typedef short short8v __attribute__((ext_vector_type(8)));
typedef float f32x4 __attribute__((ext_vector_type(4)));

// f32 -> bf16 RNE (inputs are finite; no NaN handling needed)
__device__ __forceinline__ short f2bf(float f) {
    union { float f; unsigned u; } in;
    in.f = f;
    unsigned r = in.u + 0x7FFFu + ((in.u >> 16) & 1u);
    return (short)(r >> 16);
}

// async global->LDS, 16B per lane; LDS dest is wave-uniform base + lane*16
__device__ __forceinline__ void gload_lds16(const short* g, short* l) {
    __builtin_amdgcn_global_load_lds(
        (const __attribute__((address_space(1))) unsigned int*)g,
        (__attribute__((address_space(3))) unsigned int*)l,
        16, 0, 0);
}

// ---------------------------------------------------------------------------
// Fused prep: Wu f32->bf16 convert (nt loads) + embedding gather, bid%5.
// ---------------------------------------------------------------------------
__global__ void prep(const int* __restrict__ tok,
                     const float* __restrict__ We,
                     const float* __restrict__ be,
                     const float* __restrict__ Wu,
                     short* __restrict__ Ab,   // [MTOK][EMBED] bf16
                     short* __restrict__ Bb) { // [VOCAB][EMBED] bf16
    const int bid = blockIdx.x;
    const int sub = bid % 5;
    if (sub == 4) {
        const int m = bid / 5;
        const int e = threadIdx.x * 4;
        const int t = tok[m];
        const float* w = We + (size_t)e * VOCAB + t;
        const float4 b4 = *(const float4*)(be + e);
        short4v o;
        o.x = f2bf(w[0] + b4.x);
        o.y = f2bf(w[(size_t)VOCAB] + b4.y);
        o.z = f2bf(w[(size_t)VOCAB * 2] + b4.z);
        o.w = f2bf(w[(size_t)VOCAB * 3] + b4.w);
        *(short4v*)(Ab + (size_t)m * EMBED + e) = o;
    } else {
        const int cidx = bid - bid / 5;
        const size_t i = (size_t)cidx * 2048 + (size_t)threadIdx.x * 8;
        if (i < (size_t)VOCAB * EMBED) {
            const f32x4 a = __builtin_nontemporal_load((const f32x4*)(Wu + i));
            const f32x4 b = __builtin_nontemporal_load((const f32x4*)(Wu + i) + 1);
            short8v o;
            o[0] = f2bf(a.x); o[1] = f2bf(a.y); o[2] = f2bf(a.z); o[3] = f2bf(a.w);
            o[4] = f2bf(b.x); o[5] = f2bf(b.y); o[6] = f2bf(b.z); o[7] = f2bf(b.w);
            *(short8v*)(Bb + i) = o;
        }
    }
}

// ---------------------------------------------------------------------------
// GEMM: BM=256, BN=128, BK=32; 4 waves (2M x 2N), 128x64 per wave, 16x16x32.
// m201-style fine phasing: 2 sub-phases per K-tile, each {ds_reads; stage;
// BAR; lgkmcnt(0); setprio MFMA x16; BAR}. 3 buffer pairs (72 KiB, still
// 2 blocks/CU), stage tile t+3, vmcnt(12) once per K-tile -> t+1 landed
// 2 full phases before use. XOR-swizzled LDS, nt C stores.
// ---------------------------------------------------------------------------
#define AOFFP(p) ((p) * 8192)            // A pair: [256][32] shorts = 16 KiB
#define BOFFP(p) (24576 + (p) * 4096)    // B pair: [128][32] shorts =  8 KiB

#define BAR   __builtin_amdgcn_s_barrier()
#define PRIO1 __builtin_amdgcn_s_setprio(1)
#define PRIO0 __builtin_amdgcn_s_setprio(0)
#define VMW12 asm volatile("s_waitcnt vmcnt(12)" ::: "memory")
#define LGKM0 asm volatile("s_waitcnt lgkmcnt(0)" ::: "memory")

// stage A quarter-tile [64 rows][32 shorts] (h=0..3); 256 threads cover 64 rows
#define STAGE_A(p, h, kofs) do {                                              \
    const short* _s = Ag + (size_t)(64*(h) + srow) * EMBED + (kofs) + 8*sslot;\
    gload_lds16(_s, lds + AOFFP(p) + (64*(h) + 16*w)*32);                     \
} while (0)

// stage B half-tile [64 rows][32 shorts] (h=0..1)
#define STAGE_B(p, h, kofs) do {                                              \
    const short* _s = Bg + (size_t)(64*(h) + srow) * EMBED + (kofs) + 8*sslot;\
    gload_lds16(_s, lds + BOFFP(p) + (64*(h) + 16*w)*32);                     \
} while (0)

#define STAGE6(p, kofs) do {                                                  \
    STAGE_A(p, 0, kofs); STAGE_A(p, 1, kofs);                                 \
    STAGE_A(p, 2, kofs); STAGE_A(p, 3, kofs);                                 \
    STAGE_B(p, 0, kofs); STAGE_B(p, 1, kofs);                                 \
} while (0)

// A fragments, row-half rh (rf = 4*rh .. 4*rh+3)
#define LDA4(p, rh) do {                                                      \
    _Pragma("unroll")                                                         \
    for (int rf = 0; rf < 4; ++rf)                                            \
        af[(rh)*4 + rf] = *(const bf16x8*)(lds + AOFFP(p)                     \
                              + (rA + ((rh)*4 + rf)*16)*32 + rsw);            \
} while (0)

// B fragments: 4 colfrags
#define LDB4(p) do {                                                          \
    _Pragma("unroll")                                                         \
    for (int cf = 0; cf < 4; ++cf)                                            \
        bfr[cf] = *(const bf16x8*)(lds + BOFFP(p) + (rB + cf*16)*32 + rsw);   \
} while (0)

#define MFMA16(rh) do {                                                       \
    PRIO1;                                                                    \
    _Pragma("unroll")                                                         \
    for (int cf = 0; cf < 4; ++cf)                                            \
        _Pragma("unroll")                                                     \
        for (int rf = 0; rf < 4; ++rf)                                        \
            acc[(rh)*4 + rf][cf] = __builtin_amdgcn_mfma_f32_16x16x32_bf16(   \
                af[(rh)*4 + rf], bfr[cf], acc[(rh)*4 + rf][cf], 0, 0, 0);     \
    PRIO0;                                                                    \
} while (0)

__global__ __launch_bounds__(256, 2) void gemm256x128(
        const short* __restrict__ A,   // [MTOK][EMBED] bf16
        const short* __restrict__ B,   // [VOCAB][EMBED] bf16
        const float* __restrict__ bu,  // [VOCAB]
        float* __restrict__ C) {       // [MTOK][VOCAB] f32
    extern __shared__ short lds[];

    // XCD-bijective swizzle: 4000 blocks = 8 x 500; n-major within chunk
    const int bid = blockIdx.x;
    const int T = (bid & 7) * 500 + (bid >> 3);
    const int ntile = T >> 4;            // 0..249
    const int mtile = T & 15;            // 0..15
    const int m0 = mtile << 8;
    const int n0 = ntile << 7;

    const int tid  = threadIdx.x;
    const int lane = tid & 63;
    const int w    = tid >> 6;           // wave 0..3
    const int wr   = w >> 1;             // 0..1 (M, 128 rows each)
    const int wc   = w & 1;              // 0..1 (N, 64 cols each)

    // staging decomposition: 256 threads cover [64 rows][4 slots x 16B]
    const int srow  = tid >> 2;                        // 0..63
    const int sslot = (tid & 3) ^ ((tid >> 3) & 3);    // pre-swizzled src slot

    // read-side: slot = ghi ^ ((row>>1)&3); row low bits = lane&15
    const int rA  = wr * 128 + (lane & 15);
    const int rB  = wc * 64  + (lane & 15);
    const int rsw = 8 * ((lane >> 4) ^ ((lane >> 1) & 3));

    const short* Ag = A + (size_t)m0 * EMBED;
    const short* Bg = B + (size_t)n0 * EMBED;

    f32x4 acc[8][4] = {};
    bf16x8 af[8], bfr[4];

    // prologue: tiles 0,1,2 -> pairs 0,1,2 (6 gloads each)
    STAGE6(0, 0);
    STAGE6(1, 32);
    STAGE6(2, 64);
    VMW12;                        // tile0 landed; tiles 1,2 (12) in flight
    BAR;

    int p = 0;
#pragma unroll 1
    for (int t = 0; t < 32; ++t) {
        const int kn = ((t + 3) & 31) * 32;   // tile t+3 -> pair p (wrap ok)

        // S0: reads A-quarters h0/h2 (rf0-3) + all B; stage h0,h2,Bh0
        LDA4(p, 0); LDB4(p);
        STAGE_A(p, 0, kn); STAGE_A(p, 2, kn); STAGE_B(p, 0, kn);
        BAR; LGKM0;
        MFMA16(0);
        BAR;
        // S1: reads A-quarters h1/h3 (rf4-7); stage h1,h3,Bh1
        LDA4(p, 1);
        STAGE_A(p, 1, kn); STAGE_A(p, 3, kn); STAGE_B(p, 1, kn);
        BAR; LGKM0;
        MFMA16(1);
        VMW12;                    // t+1 fully landed; t+2,t+3 (12) in flight
        BAR;

        p = (p == 2) ? 0 : p + 1;
    }

    // epilogue: C/D layout col=lane&15, row=(lane>>4)*4+q; nt stores
    const int erow0 = m0 + wr * 128 + ((lane >> 4) << 2);
    const int ecol0 = n0 + wc * 64 + (lane & 15);
#pragma unroll
    for (int cf = 0; cf < 4; ++cf) {
        const int c = ecol0 + cf * 16;
        const float bias = bu[c];
#pragma unroll
        for (int rf = 0; rf < 8; ++rf) {
            float* cp = C + (size_t)(erow0 + rf * 16) * VOCAB + c;
#pragma unroll
            for (int q = 0; q < 4; ++q)
                __builtin_nontemporal_store(acc[rf][cf][q] + bias,
                                            cp + (size_t)q * VOCAB);
        }
    }
}

extern "C" void kernel_launch(void* const* d_in, const int* in_sizes, int n_in,
                              void* d_out, int out_size, void* d_ws, size_t ws_size,
                              hipStream_t stream) {
    const int*   tok = (const int*)d_in[0];
    const float* We  = (const float*)d_in[1];
    const float* be  = (const float*)d_in[2];
    const float* Wu  = (const float*)d_in[3];
    const float* bu  = (const float*)d_in[4];
    float* C = (float*)d_out;

    short* Bb = (short*)d_ws;                        // [VOCAB][EMBED] bf16
    short* Ab = Bb + (size_t)VOCAB * EMBED;          // [MTOK][EMBED] bf16

    (void)hipFuncSetAttribute((const void*)gemm256x128,
                              hipFuncAttributeMaxDynamicSharedMemorySize,
                              73728);

    hipLaunchKernelGGL(prep, dim3(20480), dim3(256), 0, stream,
                       tok, We, be, Wu, Ab, Bb);
    // GEMM: (4096/256) * (32000/128) = 16 * 250 = 4000 blocks
    hipLaunchKernelGGL(gemm256x128, dim3(4000), dim3(256), 73728, stream,
                       Ab, Bb, bu, C);
}

// Round 10
// 405.670 us; speedup vs baseline: 1.1010x; 1.1010x over previous
//
#include <hip/hip_runtime.h>
#include <hip/hip_bf16.h>

#define VOCAB 32000
#define EMBED 1024
#define MTOK  4096   // B*T = 2*2048

typedef short bf16x8 __attribute__((ext_vector_type(8)));
typedef short short4v __attribute__((ext_vector_type(4)));
typedef short short8v __attribute__((ext_vector_type(8)));
typedef float f32x4 __attribute__((ext_vector_type(4)));

// f32 -> bf16 RNE (inputs are finite; no NaN handling needed)
__device__ __forceinline__ short f2bf(float f) {
    union { float f; unsigned u; } in;
    in.f = f;
    unsigned r = in.u + 0x7FFFu + ((in.u >> 16) & 1u);
    return (short)(r >> 16);
}

// async global->LDS, 16B per lane; LDS dest is wave-uniform base + lane*16
__device__ __forceinline__ void gload_lds16(const short* g, short* l) {
    __builtin_amdgcn_global_load_lds(
        (const __attribute__((address_space(1))) unsigned int*)g,
        (__attribute__((address_space(3))) unsigned int*)l,
        16, 0, 0);
}

// ---------------------------------------------------------------------------
// Fused prep: Wu f32->bf16 convert (nt loads) + embedding gather, bid%5.
// ---------------------------------------------------------------------------
__global__ void prep(const int* __restrict__ tok,
                     const float* __restrict__ We,
                     const float* __restrict__ be,
                     const float* __restrict__ Wu,
                     short* __restrict__ Ab,   // [MTOK][EMBED] bf16
                     short* __restrict__ Bb) { // [VOCAB][EMBED] bf16
    const int bid = blockIdx.x;
    const int sub = bid % 5;
    if (sub == 4) {
        const int m = bid / 5;
        const int e = threadIdx.x * 4;
        const int t = tok[m];
        const float* w = We + (size_t)e * VOCAB + t;
        const float4 b4 = *(const float4*)(be + e);
        short4v o;
        o.x = f2bf(w[0] + b4.x);
        o.y = f2bf(w[(size_t)VOCAB] + b4.y);
        o.z = f2bf(w[(size_t)VOCAB * 2] + b4.z);
        o.w = f2bf(w[(size_t)VOCAB * 3] + b4.w);
        *(short4v*)(Ab + (size_t)m * EMBED + e) = o;
    } else {
        const int cidx = bid - bid / 5;
        const size_t i = (size_t)cidx * 2048 + (size_t)threadIdx.x * 8;
        if (i < (size_t)VOCAB * EMBED) {
            const f32x4 a = __builtin_nontemporal_load((const f32x4*)(Wu + i));
            const f32x4 b = __builtin_nontemporal_load((const f32x4*)(Wu + i) + 1);
            short8v o;
            o[0] = f2bf(a.x); o[1] = f2bf(a.y); o[2] = f2bf(a.z); o[3] = f2bf(a.w);
            o[4] = f2bf(b.x); o[5] = f2bf(b.y); o[6] = f2bf(b.z); o[7] = f2bf(b.w);
            *(short8v*)(Bb + i) = o;
        }
    }
}

// ---------------------------------------------------------------------------
// GEMM: BM=256, BN=128, BK=32; 4 waves (2M x 2N), 128x64 per wave
// (round-6 structure, verbatim except the tile->XCD ownership map).
// XCD x owns m-slab pair {2x,2x+1} (1 MB, L2-resident) and sweeps all 250
// n-panels with the m-bit innermost; all XCDs sweep n concurrently so each
// B panel is HBM-fetched once via shared L3.
// ---------------------------------------------------------------------------
#define AOFF0 0
#define AOFF1 8192
#define BOFF0 16384
#define BOFF1 20480

#define BAR  __builtin_amdgcn_s_barrier()
#define PRIO1 __builtin_amdgcn_s_setprio(1)
#define PRIO0 __builtin_amdgcn_s_setprio(0)
#define VMW6 asm volatile("s_waitcnt vmcnt(6)" ::: "memory")

// stage A quarter-tile [64 rows][32 shorts] (h=0..3); 256 threads cover 64 rows
#define STAGE_A(boff, h, kofs) do {                                           \
    const short* _s = Ag + (size_t)(64*(h) + srow) * EMBED + (kofs) + 8*sslot;\
    gload_lds16(_s, lds + (boff) + (64*(h) + 16*w)*32);                       \
} while (0)

// stage B half-tile [64 rows][32 shorts] (h=0..1)
#define STAGE_B(boff, h, kofs) do {                                           \
    const short* _s = Bg + (size_t)(64*(h) + srow) * EMBED + (kofs) + 8*sslot;\
    gload_lds16(_s, lds + (boff) + (64*(h) + 16*w)*32);                       \
} while (0)

#define STAGE_T(ab, bb, kofs) do {                                            \
    STAGE_A(ab, 0, kofs); STAGE_A(ab, 1, kofs);                               \
    STAGE_A(ab, 2, kofs); STAGE_A(ab, 3, kofs);                               \
    STAGE_B(bb, 0, kofs); STAGE_B(bb, 1, kofs);                               \
} while (0)

// A fragments: 8 rowfrags
#define LDA8(boff) do {                                                       \
    _Pragma("unroll")                                                         \
    for (int rf = 0; rf < 8; ++rf)                                            \
        af[rf] = *(const bf16x8*)(lds + (boff) + (rA + rf*16)*32 + rsw);      \
} while (0)

// B fragments: 4 colfrags
#define LDB4(boff) do {                                                       \
    _Pragma("unroll")                                                         \
    for (int cf = 0; cf < 4; ++cf)                                            \
        bf[cf] = *(const bf16x8*)(lds + (boff) + (rB + cf*16)*32 + rsw);      \
} while (0)

#define MFMA32 do {                                                           \
    PRIO1;                                                                    \
    _Pragma("unroll")                                                         \
    for (int cf = 0; cf < 4; ++cf)                                            \
        _Pragma("unroll")                                                     \
        for (int rf = 0; rf < 8; ++rf)                                        \
            acc[rf][cf] = __builtin_amdgcn_mfma_f32_16x16x32_bf16(            \
                af[rf], bf[cf], acc[rf][cf], 0, 0, 0);                        \
    PRIO0;                                                                    \
} while (0)

__global__ __launch_bounds__(256, 2) void gemm256x128(
        const short* __restrict__ A,   // [MTOK][EMBED] bf16
        const short* __restrict__ B,   // [VOCAB][EMBED] bf16
        const float* __restrict__ bu,  // [VOCAB]
        float* __restrict__ C) {       // [MTOK][VOCAB] f32
    extern __shared__ short lds[];

    // XCD ownership map: 4000 blocks = 8 XCDs x 500.
    // XCD x -> m-slabs {2x, 2x+1}, sweeping ntile 0..249 with m-bit inner.
    const int bid   = blockIdx.x;
    const int x     = bid & 7;           // XCD (blocks round-robin over XCDs)
    const int local = bid >> 3;          // 0..499 within XCD
    const int mtile = 2 * x + (local & 1);   // 0..15
    const int ntile = local >> 1;            // 0..249
    const int m0 = mtile << 8;
    const int n0 = ntile << 7;

    const int tid  = threadIdx.x;
    const int lane = tid & 63;
    const int w    = tid >> 6;           // wave 0..3
    const int wr   = w >> 1;             // 0..1 (M, 128 rows each)
    const int wc   = w & 1;              // 0..1 (N, 64 cols each)

    // staging decomposition: 256 threads cover [64 rows][4 slots x 16B]
    const int srow  = tid >> 2;                        // 0..63
    const int sslot = (tid & 3) ^ ((tid >> 3) & 3);    // pre-swizzled src slot

    // read-side: slot = ghi ^ ((row>>1)&3); row low bits = lane&15
    const int rA  = wr * 128 + (lane & 15);
    const int rB  = wc * 64  + (lane & 15);
    const int rsw = 8 * ((lane >> 4) ^ ((lane >> 1) & 3));

    const short* Ag = A + (size_t)m0 * EMBED;
    const short* Bg = B + (size_t)n0 * EMBED;

    f32x4 acc[8][4] = {};
    bf16x8 af[8], bf[4];

    // prologue: tile0 -> buf0, tile1 -> buf1 (6 gloads each)
    STAGE_T(AOFF0, BOFF0, 0);
    STAGE_T(AOFF1, BOFF1, 32);
    VMW6;                         // tile0 landed; tile1 (6) in flight
    BAR;

#pragma unroll 1
    for (int t = 0; t < 32; ++t) {
        const int ab = (t & 1) ? AOFF1 : AOFF0;
        const int bb = (t & 1) ? BOFF1 : BOFF0;
        const int kn = ((t + 2) & 31) * 32;   // tile t+2 (wrap harmless)

        LDA8(ab); LDB4(bb);                   // frags of tile t
        STAGE_T(ab, bb, kn);                  // issue t+2 into same buf
        BAR;                                  // all waves' frag reads issued
        MFMA32;                               // lgkmcnt-gated by compiler
        VMW6;                                 // t+1 landed; t+2 in flight
        BAR;
    }

    // epilogue: C/D layout col=lane&15, row=(lane>>4)*4+q; nt stores
    const int erow0 = m0 + wr * 128 + ((lane >> 4) << 2);
    const int ecol0 = n0 + wc * 64 + (lane & 15);
#pragma unroll
    for (int cf = 0; cf < 4; ++cf) {
        const int c = ecol0 + cf * 16;
        const float bias = bu[c];
#pragma unroll
        for (int rf = 0; rf < 8; ++rf) {
            float* cp = C + (size_t)(erow0 + rf * 16) * VOCAB + c;
#pragma unroll
            for (int q = 0; q < 4; ++q)
                __builtin_nontemporal_store(acc[rf][cf][q] + bias,
                                            cp + (size_t)q * VOCAB);
        }
    }
}

extern "C" void kernel_launch(void* const* d_in, const int* in_sizes, int n_in,
                              void* d_out, int out_size, void* d_ws, size_t ws_size,
                              hipStream_t stream) {
    const int*   tok = (const int*)d_in[0];
    const float* We  = (const float*)d_in[1];
    const float* be  = (const float*)d_in[2];
    const float* Wu  = (const float*)d_in[3];
    const float* bu  = (const float*)d_in[4];
    float* C = (float*)d_out;

    short* Bb = (short*)d_ws;                        // [VOCAB][EMBED] bf16
    short* Ab = Bb + (size_t)VOCAB * EMBED;          // [MTOK][EMBED] bf16

    (void)hipFuncSetAttribute((const void*)gemm256x128,
                              hipFuncAttributeMaxDynamicSharedMemorySize,
                              49152);

    hipLaunchKernelGGL(prep, dim3(20480), dim3(256), 0, stream,
                       tok, We, be, Wu, Ab, Bb);
    // GEMM: (4096/256) * (32000/128) = 16 * 250 = 4000 blocks
    hipLaunchKernelGGL(gemm256x128, dim3(4000), dim3(256), 49152, stream,
                       Ab, Bb, bu, C);
}